// Round 7
// baseline (6329.046 us; speedup 1.0000x reference)
//
#include <hip/hip_runtime.h>

typedef __bf16 bf16;
typedef __bf16 bf16x4 __attribute__((ext_vector_type(4)));
typedef __bf16 bf16x8 __attribute__((ext_vector_type(8)));
typedef float f32x4 __attribute__((ext_vector_type(4)));
typedef unsigned long long u64;
typedef unsigned int u32;

#define T_STEPS 1024
#define BATCH   64
#define DIN     256
#define HID     1024
#define NBLK    32    // 16 feature-groups (64 feat each) x 2 batch-halves
#define RING    8     // h ring-buffer depth (slot = t & 7)
#define FSTRIDE 32    // u32s per flag -> one 128-B line per flag

// ---------------------------------------------------------------------------
// Kernel 1: xproj[t][b][h] = sum_d x[b][t][d] * w_ih[h][d]   (bf16 out)
// ---------------------------------------------------------------------------
__global__ __launch_bounds__(256) void xproj_gemm(
    const float* __restrict__ x, const float* __restrict__ w_ih,
    bf16* __restrict__ xproj)
{
    __shared__ bf16 As[128 * 40];
    __shared__ bf16 Bs[128 * 40];
    const int tid = threadIdx.x;
    const int m0 = blockIdx.x * 128;
    const int n0 = blockIdx.y * 128;
    const int w = tid >> 6, lane = tid & 63;
    const int r = lane & 15, q = lane >> 4;

    f32x4 acc[2][8];
    #pragma unroll
    for (int i = 0; i < 2; i++)
        #pragma unroll
        for (int j = 0; j < 8; j++)
            acc[i][j] = (f32x4){0.f, 0.f, 0.f, 0.f};

    for (int kk = 0; kk < 8; kk++) {
        const int k0 = kk * 32;
        __syncthreads();
        #pragma unroll
        for (int j = 0; j < 4; j++) {
            int u = tid + j * 256;
            int row = u >> 3, c4 = u & 7;
            float4 fa = *(const float4*)&x[(size_t)(m0 + row) * DIN + k0 + c4 * 4];
            bf16x4 va = { (bf16)fa.x, (bf16)fa.y, (bf16)fa.z, (bf16)fa.w };
            *(bf16x4*)&As[row * 40 + c4 * 4] = va;
            float4 fb = *(const float4*)&w_ih[(size_t)(n0 + row) * DIN + k0 + c4 * 4];
            bf16x4 vb = { (bf16)fb.x, (bf16)fb.y, (bf16)fb.z, (bf16)fb.w };
            *(bf16x4*)&Bs[row * 40 + c4 * 4] = vb;
        }
        __syncthreads();
        bf16x8 a0 = *(const bf16x8*)&As[(w * 32 + r) * 40 + q * 8];
        bf16x8 a1 = *(const bf16x8*)&As[(w * 32 + 16 + r) * 40 + q * 8];
        #pragma unroll
        for (int nt = 0; nt < 8; nt++) {
            bf16x8 bb = *(const bf16x8*)&Bs[(nt * 16 + r) * 40 + q * 8];
            acc[0][nt] = __builtin_amdgcn_mfma_f32_16x16x32_bf16(a0, bb, acc[0][nt], 0, 0, 0);
            acc[1][nt] = __builtin_amdgcn_mfma_f32_16x16x32_bf16(a1, bb, acc[1][nt], 0, 0, 0);
        }
    }

    #pragma unroll
    for (int mi = 0; mi < 2; mi++)
        #pragma unroll
        for (int nt = 0; nt < 8; nt++)
            #pragma unroll
            for (int reg = 0; reg < 4; reg++) {
                int gm = m0 + w * 32 + mi * 16 + q * 4 + reg;   // x row = b*T + t
                int n  = n0 + nt * 16 + r;
                int b  = gm >> 10, t = gm & 1023;
                xproj[(((t << 6) + b) << 10) + n] = (bf16)acc[mi][nt][reg];
            }
}

// ---------------------------------------------------------------------------
// Kernel 2: persistent recurrence, NBLK=32 blocks x 512 thr (8 waves).
// Block (fg2, half): features fg2*64..+64, batches half*32..+32.
// Waves: bg = w&1 (16-batch subgroup), kq = w>>1 (K quarter of 256).
// h broadcast volume: 32 blocks x 64 KB = 2 MB/step (4x less than R6).
// Flag lattice identical to R6 (256 flags, one 128-B line each) but published
// at 16-feature granularity by EVERY wave (each finalizes n-tile nt==kq).
// K-reduction via LDS Red with compressed slots (3 writers per n-tile).
// ---------------------------------------------------------------------------
__global__ __launch_bounds__(512, 2) void rnn_rec(
    const float* __restrict__ w_hh, const float* __restrict__ b_mod,
    const bf16* __restrict__ xproj, u64* __restrict__ hbuf,
    float* __restrict__ hT, u32* __restrict__ flags)
{
    __shared__ bf16 Wl[64 * 1032];       // 132 KB, +8 pad
    __shared__ float Red[24 * 272];      // 25.5 KB: [bg][nt][slot] stride 272

    const int tid = threadIdx.x;
    const int fg2 = (int)(blockIdx.x >> 1);   // 0..15
    const int half = (int)(blockIdx.x & 1);
    const int f0 = fg2 * 64;
    const int b0 = half * 32;
    const int w = tid >> 6, lane = tid & 63;
    const int r = lane & 15, q = lane >> 4;
    const int bg = w & 1, kq = w >> 1;
    const int batchA = b0 + bg * 16 + r;       // A-frag row = batch

    // Stage W rows f0..f0+63 (fp32 -> bf16) into LDS, once.
    for (int j = 0; j < 32; j++) {
        int u = tid + j * 512;                  // float4 units, 0..16383
        int row = u >> 8, c4 = u & 255;
        float4 f = *(const float4*)&w_hh[(size_t)(f0 + row) * HID + c4 * 4];
        bf16x4 v = { (bf16)f.x, (bf16)f.y, (bf16)f.z, (bf16)f.w };
        *(bf16x4*)&Wl[row * 1032 + c4 * 4] = v;
    }
    const int myF = f0 + kq * 16 + r;          // feature this lane finalizes
    const float bc = b_mod[myF];
    __syncthreads();

    // Hoist B fragments: 4 n-tiles x 8 k-steps (loop-invariant, 128 VGPRs).
    bf16x8 Bf[4][8];
    #pragma unroll
    for (int nt = 0; nt < 4; nt++)
        #pragma unroll
        for (int ks = 0; ks < 8; ks++)
            Bf[nt][ks] = *(const bf16x8*)&Wl[(nt * 16 + r) * 1032 + kq * 256 + ks * 32 + q * 8];

    u32* hbuf32 = (u32*)hbuf;
    const int dom = (half << 1) + bg;          // flag domain
    // poll: features [256kq, +256) = flag groups 16kq..16kq+15 (one line each)
    u32* pollFlag = flags + (size_t)(dom * 64 + kq * 16 + r) * FSTRIDE;
    // publish: my 16-feature group fg2*4 + kq
    u32* pubFlag  = flags + (size_t)(dom * 64 + fg2 * 4 + kq) * FSTRIDE;

    // xproj prefetch for t=0 (every wave finalizes its own slice now)
    float xpv[4];
    #pragma unroll
    for (int reg = 0; reg < 4; reg++) {
        int b = b0 + bg * 16 + q * 4 + reg;
        xpv[reg] = (float)xproj[(b << 10) + myF];
    }

    for (int t = 0; t < T_STEPS; t++) {
        const int rp = t & (RING - 1), wp = (t + 1) & (RING - 1);

        // ---- wait for MY 16 producer groups (one gather, 16 distinct lines)
        const u32 tgt = (u32)t;
        for (;;) {
            u32 f = __hip_atomic_load(pollFlag, __ATOMIC_RELAXED, __HIP_MEMORY_SCOPE_AGENT);
            if (__all((int)(f >= tgt))) break;
        }

        // ---- load my K-quarter A fragments (coherent u64 loads) ----
        const u64* H = hbuf + (size_t)rp * 16384 + batchA * 256 + kq * 64 + q * 2;
        union { u64 u[2]; bf16x8 v; } A[8];
        #pragma unroll
        for (int ks = 0; ks < 8; ks++) {
            A[ks].u[0] = __hip_atomic_load(&H[ks*8    ], __ATOMIC_RELAXED, __HIP_MEMORY_SCOPE_AGENT);
            A[ks].u[1] = __hip_atomic_load(&H[ks*8 + 1], __ATOMIC_RELAXED, __HIP_MEMORY_SCOPE_AGENT);
        }

        f32x4 acc[4];
        #pragma unroll
        for (int nt = 0; nt < 4; nt++) acc[nt] = (f32x4){0.f,0.f,0.f,0.f};
        #pragma unroll
        for (int ks = 0; ks < 8; ks++)
            #pragma unroll
            for (int nt = 0; nt < 4; nt++)
                acc[nt] = __builtin_amdgcn_mfma_f32_16x16x32_bf16(A[ks].v, Bf[nt][ks], acc[nt], 0, 0, 0);

        // K-partials for the n-tiles I don't finalize -> LDS
        #pragma unroll
        for (int nt = 0; nt < 4; nt++) {
            if (nt == kq) continue;
            const int s = (kq - nt - 1) & 3;           // 0..2
            const int base = ((bg * 4 + nt) * 3 + s) * 272;
            #pragma unroll
            for (int reg = 0; reg < 4; reg++)
                Red[base + (q * 4 + reg) * 17 + r] = acc[nt][reg];
        }
        __syncthreads();

        // finalize my n-tile (nt == kq): 16 features x 16 batches
        float hv4[4];
        #pragma unroll
        for (int reg = 0; reg < 4; reg++) {
            float z = acc[kq][reg];
            #pragma unroll
            for (int s = 0; s < 3; s++)
                z += Red[((bg * 4 + kq) * 3 + s) * 272 + (q * 4 + reg) * 17 + r];
            z += xpv[reg];
            hv4[reg] = copysignf(fmaxf(fabsf(z) + bc, 0.0f), z);
        }
        __syncthreads();   // Red reuse guard (reads done above)

        if (t == T_STEPS - 1) {
            #pragma unroll
            for (int reg = 0; reg < 4; reg++)
                hT[myF * 64 + b0 + bg * 16 + q * 4 + reg] = hv4[reg];  // fp32 [H][B]
        } else {
            #pragma unroll
            for (int reg = 0; reg < 4; reg++) {
                const int b = b0 + bg * 16 + q * 4 + reg;
                float other = __shfl_xor(hv4[reg], 1);
                if ((r & 1) == 0) {
                    u32 lo = (u32)__builtin_bit_cast(unsigned short, (bf16)hv4[reg]);
                    u32 hi = (u32)__builtin_bit_cast(unsigned short, (bf16)other);
                    __hip_atomic_store(&hbuf32[(size_t)wp * 32768 + (b << 9) + (myF >> 1)],
                                       lo | (hi << 16), __ATOMIC_RELAXED, __HIP_MEMORY_SCOPE_AGENT);
                }
            }
            // publish: wave-local drain, then flag store (lane 0)
            asm volatile("s_waitcnt vmcnt(0)" ::: "memory");
            if (lane == 0)
                __hip_atomic_store(pubFlag, (u32)(t + 1), __ATOMIC_RELAXED, __HIP_MEMORY_SCOPE_AGENT);
            // prefetch next step's xproj AFTER the drain+flag (off the chain)
            #pragma unroll
            for (int reg = 0; reg < 4; reg++) {
                int b = b0 + bg * 16 + q * 4 + reg;
                xpv[reg] = (float)xproj[((size_t)(t + 1) << 16) + (b << 10) + myF];
            }
        }
    }
}

// ---------------------------------------------------------------------------
// Kernel 3: out[b][c] = hT[:,b] . w_fc[c,:] + b_fc[c]   (fp32)
// ---------------------------------------------------------------------------
__global__ __launch_bounds__(256) void fc_head(
    const float* __restrict__ hT, const float* __restrict__ w_fc,
    const float* __restrict__ b_fc, float* __restrict__ out)
{
    const int tid = threadIdx.x;
    const int b = tid & 63;
    const int c = blockIdx.x * 4 + (tid >> 6);
    float acc = b_fc[c];
    #pragma unroll 8
    for (int k = 0; k < HID; k++)
        acc = fmaf(hT[k * 64 + b], w_fc[(size_t)c * HID + k], acc);
    out[b * 1000 + c] = acc;
}

// ---------------------------------------------------------------------------
extern "C" void kernel_launch(void* const* d_in, const int* in_sizes, int n_in,
                              void* d_out, int out_size, void* d_ws, size_t ws_size,
                              hipStream_t stream)
{
    const float* x     = (const float*)d_in[0];
    const float* w_ih  = (const float*)d_in[1];
    const float* w_hh  = (const float*)d_in[2];
    const float* b_mod = (const float*)d_in[3];
    const float* w_fc  = (const float*)d_in[4];
    const float* b_fc  = (const float*)d_in[5];
    float* out = (float*)d_out;

    char* ws = (char*)d_ws;
    // ws layout:
    //   [0, 128 MiB)              xproj bf16  [T][B][H]
    //   [+0, +1 MiB)              hbuf bf16   ring[8][B][H]
    //   [+1 MiB, +1.25 MiB)       hT fp32     [H][B]
    //   [+1.25 MiB, +1.25M+32K)   flags u32   [half][bg][group16] x FSTRIDE
    bf16*  xproj = (bf16*)ws;
    u64*   hbuf  = (u64*)(ws + 134217728);
    float* hT    = (float*)(ws + 134217728 + 1048576);
    u32*   flags = (u32*)(ws + 134217728 + 1048576 + 262144);

    // zero h ring slot 0 (t=0 input) and flags (ws is poisoned 0xAA)
    hipMemsetAsync(hbuf, 0, 131072, stream);
    hipMemsetAsync(flags, 0, 256 * FSTRIDE * 4, stream);

    dim3 g1(512, 8);
    xproj_gemm<<<g1, 256, 0, stream>>>(x, w_ih, xproj);
    rnn_rec<<<NBLK, 512, 0, stream>>>(w_hh, b_mod, xproj, hbuf, hT, flags);
    fc_head<<<250, 256, 0, stream>>>(hT, w_fc, b_fc, out);
}

// Round 8
// 5022.244 us; speedup vs baseline: 1.2602x; 1.2602x over previous
//
#include <hip/hip_runtime.h>

typedef __bf16 bf16;
typedef __bf16 bf16x4 __attribute__((ext_vector_type(4)));
typedef __bf16 bf16x8 __attribute__((ext_vector_type(8)));
typedef float f32x4 __attribute__((ext_vector_type(4)));
typedef int   i32x4 __attribute__((ext_vector_type(4)));
typedef unsigned long long u64;
typedef unsigned int u32;

#define T_STEPS 1024
#define BATCH   64
#define DIN     256
#define HID     1024
#define NBLK    32    // 16 feature-groups (64 feat each) x 2 batch-halves
#define RING    8     // h ring-buffer depth (slot = t & 7)
#define SENT    0x7F7F7F7Fu   // two bf16 3.39e38 — unreachable by the RNN

// ---------------------------------------------------------------------------
// Kernel 1: xproj[t][b][h] = sum_d x[b][t][d] * w_ih[h][d]   (bf16 out)
// ---------------------------------------------------------------------------
__global__ __launch_bounds__(256) void xproj_gemm(
    const float* __restrict__ x, const float* __restrict__ w_ih,
    bf16* __restrict__ xproj)
{
    __shared__ bf16 As[128 * 40];
    __shared__ bf16 Bs[128 * 40];
    const int tid = threadIdx.x;
    const int m0 = blockIdx.x * 128;
    const int n0 = blockIdx.y * 128;
    const int w = tid >> 6, lane = tid & 63;
    const int r = lane & 15, q = lane >> 4;

    f32x4 acc[2][8];
    #pragma unroll
    for (int i = 0; i < 2; i++)
        #pragma unroll
        for (int j = 0; j < 8; j++)
            acc[i][j] = (f32x4){0.f, 0.f, 0.f, 0.f};

    for (int kk = 0; kk < 8; kk++) {
        const int k0 = kk * 32;
        __syncthreads();
        #pragma unroll
        for (int j = 0; j < 4; j++) {
            int u = tid + j * 256;
            int row = u >> 3, c4 = u & 7;
            float4 fa = *(const float4*)&x[(size_t)(m0 + row) * DIN + k0 + c4 * 4];
            bf16x4 va = { (bf16)fa.x, (bf16)fa.y, (bf16)fa.z, (bf16)fa.w };
            *(bf16x4*)&As[row * 40 + c4 * 4] = va;
            float4 fb = *(const float4*)&w_ih[(size_t)(n0 + row) * DIN + k0 + c4 * 4];
            bf16x4 vb = { (bf16)fb.x, (bf16)fb.y, (bf16)fb.z, (bf16)fb.w };
            *(bf16x4*)&Bs[row * 40 + c4 * 4] = vb;
        }
        __syncthreads();
        bf16x8 a0 = *(const bf16x8*)&As[(w * 32 + r) * 40 + q * 8];
        bf16x8 a1 = *(const bf16x8*)&As[(w * 32 + 16 + r) * 40 + q * 8];
        #pragma unroll
        for (int nt = 0; nt < 8; nt++) {
            bf16x8 bb = *(const bf16x8*)&Bs[(nt * 16 + r) * 40 + q * 8];
            acc[0][nt] = __builtin_amdgcn_mfma_f32_16x16x32_bf16(a0, bb, acc[0][nt], 0, 0, 0);
            acc[1][nt] = __builtin_amdgcn_mfma_f32_16x16x32_bf16(a1, bb, acc[1][nt], 0, 0, 0);
        }
    }

    #pragma unroll
    for (int mi = 0; mi < 2; mi++)
        #pragma unroll
        for (int nt = 0; nt < 8; nt++)
            #pragma unroll
            for (int reg = 0; reg < 4; reg++) {
                int gm = m0 + w * 32 + mi * 16 + q * 4 + reg;   // x row = b*T + t
                int n  = n0 + nt * 16 + r;
                int b  = gm >> 10, t = gm & 1023;
                xproj[(((t << 6) + b) << 10) + n] = (bf16)acc[mi][nt][reg];
            }
}

// ---------------------------------------------------------------------------
// Kernel 2: persistent recurrence, NBLK=32 blocks x 512 thr (8 waves).
// Block (fg2, half): features fg2*64..+64, batches half*32..+32.
// Waves: bg = w&1 (16-batch subgroup), kq = w>>1 (K quarter of 256).
// NO FLAGS: h data is self-validating. A u32 word is either SENT (unwritten
// this generation) or a final value (u32 stores are atomic). The consumer's
// poll load IS the data load -> chain = store-visible + observe (2 hops).
// Ring of 8 slots; each producer wave re-sentinels its own region of slot
// (t+4)&7 during step t (readers of that slot's old generation are >=3 steps
// done; skew within a (half,bg) domain is <=1 step by the dependency chain;
// sentinel->data store order enforced by the per-step vmcnt(0) drain).
// Slots 1..7 memset to 0x7F at launch; slot 0 = h0 = 0 (passes instantly).
// ---------------------------------------------------------------------------
__global__ __launch_bounds__(512, 2) void rnn_rec(
    const float* __restrict__ w_hh, const float* __restrict__ b_mod,
    const bf16* __restrict__ xproj, u64* __restrict__ hbuf,
    float* __restrict__ hT)
{
    __shared__ bf16 Wl[64 * 1032];       // 132 KB, +8 pad
    __shared__ float Red[24 * 272];      // 25.5 KB: [bg][nt][slot] stride 272

    const int tid = threadIdx.x;
    const int fg2 = (int)(blockIdx.x >> 1);   // 0..15
    const int half = (int)(blockIdx.x & 1);
    const int f0 = fg2 * 64;
    const int b0 = half * 32;
    const int w = tid >> 6, lane = tid & 63;
    const int r = lane & 15, q = lane >> 4;
    const int bg = w & 1, kq = w >> 1;
    const int batchA = b0 + bg * 16 + r;       // A-frag row = batch

    // Stage W rows f0..f0+63 (fp32 -> bf16) into LDS, once.
    for (int j = 0; j < 32; j++) {
        int u = tid + j * 512;                  // float4 units, 0..16383
        int row = u >> 8, c4 = u & 255;
        float4 f = *(const float4*)&w_hh[(size_t)(f0 + row) * HID + c4 * 4];
        bf16x4 v = { (bf16)f.x, (bf16)f.y, (bf16)f.z, (bf16)f.w };
        *(bf16x4*)&Wl[row * 1032 + c4 * 4] = v;
    }
    const int myF = f0 + kq * 16 + r;          // feature this lane finalizes
    const float bc = b_mod[myF];
    __syncthreads();

    // Hoist B fragments: 4 n-tiles x 8 k-steps (loop-invariant).
    bf16x8 Bf[4][8];
    #pragma unroll
    for (int nt = 0; nt < 4; nt++)
        #pragma unroll
        for (int ks = 0; ks < 8; ks++)
            Bf[nt][ks] = *(const bf16x8*)&Wl[(nt * 16 + r) * 1032 + kq * 256 + ks * 32 + q * 8];

    u32* hbuf32 = (u32*)hbuf;
    // per-lane base of my A-fragment inside a slot (bytes)
    const size_t fragOff = (size_t)batchA * 2048 + kq * 512 + q * 16;

    // xproj prefetch for t=0
    float xpv[4];
    #pragma unroll
    for (int reg = 0; reg < 4; reg++) {
        int b = b0 + bg * 16 + q * 4 + reg;
        xpv[reg] = (float)xproj[(b << 10) + myF];
    }

    for (int t = 0; t < T_STEPS; t++) {
        const int rp = t & (RING - 1), wp = (t + 1) & (RING - 1);
        const char* Hb = (const char*)hbuf + (size_t)rp * 131072 + fragOff;

        // ---- self-validating poll: load my fragment until sentinel-free ----
        union { i32x4 v[8]; u32 wd[32]; bf16x8 f[8]; } A;
        for (;;) {
            asm volatile(
                "global_load_dwordx4 %0, %8, off sc0 sc1\n\t"
                "global_load_dwordx4 %1, %8, off offset:64 sc0 sc1\n\t"
                "global_load_dwordx4 %2, %8, off offset:128 sc0 sc1\n\t"
                "global_load_dwordx4 %3, %8, off offset:192 sc0 sc1\n\t"
                "global_load_dwordx4 %4, %8, off offset:256 sc0 sc1\n\t"
                "global_load_dwordx4 %5, %8, off offset:320 sc0 sc1\n\t"
                "global_load_dwordx4 %6, %8, off offset:384 sc0 sc1\n\t"
                "global_load_dwordx4 %7, %8, off offset:448 sc0 sc1\n\t"
                "s_waitcnt vmcnt(0)"
                : "=v"(A.v[0]), "=v"(A.v[1]), "=v"(A.v[2]), "=v"(A.v[3]),
                  "=v"(A.v[4]), "=v"(A.v[5]), "=v"(A.v[6]), "=v"(A.v[7])
                : "v"(Hb)
                : "memory");
            bool ok = true;
            #pragma unroll
            for (int i = 0; i < 32; i++) ok &= (A.wd[i] != SENT);
            if (__all((int)ok)) break;
        }

        f32x4 acc[4];
        #pragma unroll
        for (int nt = 0; nt < 4; nt++) acc[nt] = (f32x4){0.f,0.f,0.f,0.f};
        #pragma unroll
        for (int ks = 0; ks < 8; ks++)
            #pragma unroll
            for (int nt = 0; nt < 4; nt++)
                acc[nt] = __builtin_amdgcn_mfma_f32_16x16x32_bf16(A.f[ks], Bf[nt][ks], acc[nt], 0, 0, 0);

        // K-partials for the n-tiles I don't finalize -> LDS
        #pragma unroll
        for (int nt = 0; nt < 4; nt++) {
            if (nt == kq) continue;
            const int s = (kq - nt - 1) & 3;           // 0..2
            const int base = ((bg * 4 + nt) * 3 + s) * 272;
            #pragma unroll
            for (int reg = 0; reg < 4; reg++)
                Red[base + (q * 4 + reg) * 17 + r] = acc[nt][reg];
        }
        __syncthreads();

        // finalize my n-tile (nt == kq): 16 features x 16 batches
        float hv4[4];
        #pragma unroll
        for (int reg = 0; reg < 4; reg++) {
            float z = acc[kq][reg];
            #pragma unroll
            for (int s = 0; s < 3; s++)
                z += Red[((bg * 4 + kq) * 3 + s) * 272 + (q * 4 + reg) * 17 + r];
            z += xpv[reg];
            hv4[reg] = copysignf(fmaxf(fabsf(z) + bc, 0.0f), z);
        }
        __syncthreads();   // Red reuse guard (reads done above)

        if (t == T_STEPS - 1) {
            #pragma unroll
            for (int reg = 0; reg < 4; reg++)
                hT[myF * 64 + b0 + bg * 16 + q * 4 + reg] = hv4[reg];  // fp32 [H][B]
        } else {
            // store h_{t+1} into slot wp (u32-atomic coherent stores)
            #pragma unroll
            for (int reg = 0; reg < 4; reg++) {
                const int b = b0 + bg * 16 + q * 4 + reg;
                float other = __shfl_xor(hv4[reg], 1);
                if ((r & 1) == 0) {
                    u32 lo = (u32)__builtin_bit_cast(unsigned short, (bf16)hv4[reg]);
                    u32 hi = (u32)__builtin_bit_cast(unsigned short, (bf16)other);
                    __hip_atomic_store(&hbuf32[(size_t)wp * 32768 + (b << 9) + (myF >> 1)],
                                       lo | (hi << 16), __ATOMIC_RELAXED, __HIP_MEMORY_SCOPE_AGENT);
                }
            }
            // re-sentinel my region of slot (t+4)&7 (next generation prep;
            // ordered before my step-(t+3) data write by next poll's vmcnt(0))
            const size_t sp = (size_t)((t + 4) & (RING - 1)) * 32768;
            #pragma unroll
            for (int reg = 0; reg < 4; reg++) {
                const int b = b0 + bg * 16 + q * 4 + reg;
                if ((r & 1) == 0)
                    __hip_atomic_store(&hbuf32[sp + (b << 9) + (myF >> 1)],
                                       SENT, __ATOMIC_RELAXED, __HIP_MEMORY_SCOPE_AGENT);
            }
            // prefetch next step's xproj (off the critical chain)
            #pragma unroll
            for (int reg = 0; reg < 4; reg++) {
                int b = b0 + bg * 16 + q * 4 + reg;
                xpv[reg] = (float)xproj[((size_t)(t + 1) << 16) + (b << 10) + myF];
            }
        }
    }
}

// ---------------------------------------------------------------------------
// Kernel 3: out[b][c] = hT[:,b] . w_fc[c,:] + b_fc[c]   (fp32)
// ---------------------------------------------------------------------------
__global__ __launch_bounds__(256) void fc_head(
    const float* __restrict__ hT, const float* __restrict__ w_fc,
    const float* __restrict__ b_fc, float* __restrict__ out)
{
    const int tid = threadIdx.x;
    const int b = tid & 63;
    const int c = blockIdx.x * 4 + (tid >> 6);
    float acc = b_fc[c];
    #pragma unroll 8
    for (int k = 0; k < HID; k++)
        acc = fmaf(hT[k * 64 + b], w_fc[(size_t)c * HID + k], acc);
    out[b * 1000 + c] = acc;
}

// ---------------------------------------------------------------------------
extern "C" void kernel_launch(void* const* d_in, const int* in_sizes, int n_in,
                              void* d_out, int out_size, void* d_ws, size_t ws_size,
                              hipStream_t stream)
{
    const float* x     = (const float*)d_in[0];
    const float* w_ih  = (const float*)d_in[1];
    const float* w_hh  = (const float*)d_in[2];
    const float* b_mod = (const float*)d_in[3];
    const float* w_fc  = (const float*)d_in[4];
    const float* b_fc  = (const float*)d_in[5];
    float* out = (float*)d_out;

    char* ws = (char*)d_ws;
    // ws layout:
    //   [0, 128 MiB)              xproj bf16  [T][B][H]
    //   [+0, +1 MiB)              hbuf bf16   ring[8][B][H]
    //   [+1 MiB, +1.25 MiB)       hT fp32     [H][B]
    bf16*  xproj = (bf16*)ws;
    u64*   hbuf  = (u64*)(ws + 134217728);
    float* hT    = (float*)(ws + 134217728 + 1048576);

    // ring init: slot 0 = h0 = 0 (valid data), slots 1..7 = sentinel bytes
    hipMemsetAsync(hbuf, 0, 131072, stream);
    hipMemsetAsync((char*)hbuf + 131072, 0x7F, 7 * 131072, stream);

    dim3 g1(512, 8);
    xproj_gemm<<<g1, 256, 0, stream>>>(x, w_ih, xproj);
    rnn_rec<<<NBLK, 512, 0, stream>>>(w_hh, b_mod, xproj, hbuf, hT);
    fc_head<<<250, 256, 0, stream>>>(hT, w_fc, b_fc, out);
}